// Round 15
// baseline (300.903 us; speedup 1.0000x reference)
//
#include <hip/hip_runtime.h>

// ChebyshevGCNN: out = relu(bias + x@W0 + T1@W1 + T2@W2 + T3@W3)
// Reassociated: S1=Lx, S2=LS1, S3=LS2;  T2=2S2-x, T3=4S3-3S1
//   => out = relu(bias + x@(W0-W2) + S1@(W1-3W3) + S2@(2W2) + S3@(4W3))
// Round 15: restore best spmm (u8, 8 edges in flight, in-loop scale, EPB 8192);
// CSR build with ONE histogram pass: hist writes per-block bucket counts,
// scan2 exclusive-scans [bucket][block], scatter prefills cursors and does a
// single edge loop. spmm is at the ~5 TB/s random-gather ceiling.

#define N_NODES 50000
#define N_EDGES 800000
#define BATCH 4
#define CH 64
#define BN (N_NODES * CH)             // elems per batch matrix (out layout)
#define ROWS_TOTAL (BATCH * N_NODES)  // 200,000
#define NB 782                        // buckets of 64 rows: 782*64 = 50048
#define EPB 8192                      // edges per block in bucket passes
#define SCT_BLOCKS ((N_EDGES + EPB - 1) / EPB)  // 98
#define TOTC (NB * SCT_BLOCKS)        // 76,636 per-(bucket,block) counts

typedef unsigned int uint;
typedef unsigned short ushort;
typedef unsigned char uchar;
typedef __attribute__((ext_vector_type(8))) short short8;   // 8 x bf16
typedef __attribute__((ext_vector_type(4))) float f32x4;

__device__ __forceinline__ uint pack_bf16(float lo, float hi) {
  uint a = __float_as_uint(lo);
  uint b = __float_as_uint(hi);
  a = (a + 0x7fffu + ((a >> 16) & 1u)) >> 16;  // RN-even
  b = (b + 0x7fffu + ((b >> 16) & 1u)) >> 16;
  return a | (b << 16);
}
__device__ __forceinline__ ushort bf16one(float x) {
  uint a = __float_as_uint(x);
  a = (a + 0x7fffu + ((a >> 16) & 1u)) >> 16;
  return (ushort)a;
}
// quantize to biased u8: (rint(v*inv)+128)
__device__ __forceinline__ uint q_u8(float v, float inv) {
  return (uint)((int)rintf(v * inv) + 128) & 0xffu;
}

// ---------------- CSR build: counting sort, single histogram ----------------
// 1/4: per-(block,bucket) histogram -> bcounts[b * SCT_BLOCKS + blk]
__global__ __launch_bounds__(1024) void bucket_hist(const int* __restrict__ rows,
                                                    int* __restrict__ bcounts) {
  __shared__ int h[NB];
  for (int b = threadIdx.x; b < NB; b += 1024) h[b] = 0;
  __syncthreads();
  int base_e = blockIdx.x * EPB;
#pragma unroll
  for (int j = 0; j < EPB / 1024; ++j) {
    int e = base_e + j * 1024 + threadIdx.x;
    if (e < N_EDGES) atomicAdd(&h[rows[e] >> 6], 1);
  }
  __syncthreads();
  for (int b = threadIdx.x; b < NB; b += 1024)
    bcounts[(size_t)b * SCT_BLOCKS + blockIdx.x] = h[b];
}

// 2/4: exclusive scan of all 76,636 counts (bucket-major) -> bases
__global__ __launch_bounds__(1024) void scan2_kernel(const int* __restrict__ bc,
                                                     int* __restrict__ bases) {
  __shared__ int sums[1024];
  int tid = threadIdx.x;
  const int per = (TOTC + 1023) / 1024;  // 75
  int begin = tid * per;
  int end = begin + per; if (end > TOTC) end = TOTC;
  int s = 0;
  for (int i = begin; i < end; ++i) s += bc[i];
  sums[tid] = s;
  __syncthreads();
  for (int off = 1; off < 1024; off <<= 1) {
    int t = (tid >= off) ? sums[tid - off] : 0;
    __syncthreads();
    sums[tid] += t;
    __syncthreads();
  }
  int running = sums[tid] - s;  // exclusive prefix
  for (int i = begin; i < end; ++i) {
    bases[i] = running;
    running += bc[i];
  }
}

// 3/4: scatter edges; cursors prefilled from scanned bases (single edge loop)
__global__ __launch_bounds__(1024) void bucket_scatter(const int* __restrict__ rows,
                                                       const int* __restrict__ cols,
                                                       const float* __restrict__ vals,
                                                       const int* __restrict__ bases,
                                                       uint2* __restrict__ staging) {
  __shared__ int lcur[NB];
  for (int b = threadIdx.x; b < NB; b += 1024)
    lcur[b] = bases[(size_t)b * SCT_BLOCKS + blockIdx.x];
  __syncthreads();
  int base_e = blockIdx.x * EPB;
#pragma unroll
  for (int j = 0; j < EPB / 1024; ++j) {
    int e = base_e + j * 1024 + threadIdx.x;
    if (e < N_EDGES) {
      int r = rows[e];
      int pos = atomicAdd(&lcur[r >> 6], 1);
      staging[pos] = make_uint2((uint)cols[e] | ((uint)(r & 63) << 20),
                                __float_as_uint(vals[e]));
    }
  }
}

// 4/4: within each bucket, group by exact row; emit pairs + row_start.
__global__ __launch_bounds__(256) void bucket_finalize(const int* __restrict__ bases,
                                                       const uint2* __restrict__ staging,
                                                       uint2* __restrict__ pairs,
                                                       int* __restrict__ row_start) {
  int b = blockIdx.x;
  int seg0 = bases[(size_t)b * SCT_BLOCKS];
  int seg1 = (b == NB - 1) ? N_EDGES : bases[(size_t)(b + 1) * SCT_BLOCKS];
  __shared__ int hist[64];
  __shared__ int cur[64];
  if (threadIdx.x < 64) hist[threadIdx.x] = 0;
  __syncthreads();
  for (int i = seg0 + threadIdx.x; i < seg1; i += 256)
    atomicAdd(&hist[staging[i].x >> 20], 1);
  __syncthreads();
  if (threadIdx.x < 64) {
    int v = hist[threadIdx.x];
    int sc = v;
#pragma unroll
    for (int off = 1; off < 64; off <<= 1) {
      int t = __shfl_up(sc, off, 64);
      if (threadIdx.x >= (unsigned)off) sc += t;
    }
    int start = seg0 + sc - v;  // exclusive
    cur[threadIdx.x] = start;
    int r = b * 64 + threadIdx.x;
    if (r < N_NODES) row_start[r] = start;
    if (r == N_NODES) row_start[N_NODES] = N_EDGES;
  }
  __syncthreads();
  for (int i = seg0 + threadIdx.x; i < seg1; i += 256) {
    uint2 eu = staging[i];
    int rl = eu.x >> 20;
    int pos = atomicAdd(&cur[rl], 1);
    pairs[pos] = make_uint2(eu.x & 0xFFFFFu, eu.y);
  }
}

// Modified weights, transposed + bf16: wtT[o][k], k = m*64+c, m in 0..3.
__global__ __launch_bounds__(256) void wprep_kernel(const float* __restrict__ w,
                                                    ushort* __restrict__ wtT) {
  int t = blockIdx.x * 256 + threadIdx.x;
  if (t >= 64 * 256) return;
  int o = t >> 8, k = t & 255, m = k >> 6, c = k & 63;
  int idx = c * 64 + o;
  float v;
  if (m == 0)      v = w[idx] - w[2 * 4096 + idx];
  else if (m == 1) v = w[4096 + idx] - 3.0f * w[3 * 4096 + idx];
  else if (m == 2) v = 2.0f * w[2 * 4096 + idx];
  else             v = 4.0f * w[3 * 4096 + idx];
  wtT[t] = bf16one(v);
}

// One wave per node: f32 [b][node][64] -> biased-u8 [node][b][64] + scale.
__global__ __launch_bounds__(256) void cvt_kernel(const float* __restrict__ in,
                                                  uint* __restrict__ xu8w,
                                                  float* __restrict__ xsc) {
  int node = blockIdx.x * 4 + (threadIdx.x >> 6);
  int lane = threadIdx.x & 63;
  int b = lane >> 4;
  int c4 = (lane & 15) * 4;
  float4 v = *reinterpret_cast<const float4*>(in + (size_t)b * BN + (size_t)node * 64 + c4);
  float mx = fmaxf(fmaxf(fabsf(v.x), fabsf(v.y)), fmaxf(fabsf(v.z), fabsf(v.w)));
#pragma unroll
  for (int off = 1; off < 64; off <<= 1) mx = fmaxf(mx, __shfl_xor(mx, off, 64));
  float inv = mx > 0.f ? 127.0f / mx : 0.f;
  uint w8 = q_u8(v.x, inv) | (q_u8(v.y, inv) << 8) |
            (q_u8(v.z, inv) << 16) | (q_u8(v.w, inv) << 24);
  xu8w[(size_t)node * 64 + b * 16 + (lane & 15)] = w8;
  if (lane == 0) xsc[node] = mx * (1.0f / 127.0f);
}

// decode 16 biased-u8 values: acc += m * u (bias handled via sm)
__device__ __forceinline__ void fma16_u8(float acc[16], float& sm, float m,
                                         const uint4& w) {
  const uint arr[4] = {w.x, w.y, w.z, w.w};
#pragma unroll
  for (int t = 0; t < 4; ++t) {
    uint u = arr[t];
    acc[t * 4 + 0] = fmaf(m, (float)(u & 0xffu),         acc[t * 4 + 0]);
    acc[t * 4 + 1] = fmaf(m, (float)((u >> 8) & 0xffu),  acc[t * 4 + 1]);
    acc[t * 4 + 2] = fmaf(m, (float)((u >> 16) & 0xffu), acc[t * 4 + 2]);
    acc[t * 4 + 3] = fmaf(m, (float)(u >> 24),           acc[t * 4 + 3]);
  }
  sm += m;
}

// dst = L * src, biased-u8 in/out, per-node scales. One wave per dest node.
// 16 lanes x 16B = one 256B edge block, 4 edges per VMEM instruction,
// 2-deep unroll (8 edges in flight). value=(u-128)*sc folded via acc-128*sm.
__device__ __forceinline__ void spmm_body(const int* __restrict__ row_start,
                                          const uint2* __restrict__ pairs,
                                          const uchar* __restrict__ src,
                                          const float* __restrict__ ssc,
                                          uchar* __restrict__ dst,
                                          float* __restrict__ dsc) {
  int row = blockIdx.x * 4 + (threadIdx.x >> 6);
  int lane = threadIdx.x & 63;
  int q = lane >> 4;
  int ql = lane & 15;
  const uchar* sb = src + ql * 16;
  int s = row_start[row], e = row_start[row + 1];
  float acc[16];
  float sm = 0.f;
#pragma unroll
  for (int j = 0; j < 16; ++j) acc[j] = 0.f;
  int i = s;
  for (; i + 7 < e; i += 8) {
    uint2 pa = pairs[i + q];
    uint2 pb = pairs[i + 4 + q];
    uint4 qa = *reinterpret_cast<const uint4*>(sb + (size_t)pa.x * 256);
    uint4 qb = *reinterpret_cast<const uint4*>(sb + (size_t)pb.x * 256);
    float ma = __uint_as_float(pa.y) * ssc[pa.x];
    float mb = __uint_as_float(pb.y) * ssc[pb.x];
    fma16_u8(acc, sm, ma, qa);
    fma16_u8(acc, sm, mb, qb);
  }
  for (; i < e; i += 4) {
    if (i + q < e) {
      uint2 p0 = pairs[i + q];
      uint4 q0 = *reinterpret_cast<const uint4*>(sb + (size_t)p0.x * 256);
      fma16_u8(acc, sm, __uint_as_float(p0.y) * ssc[p0.x], q0);
    }
  }
  // fold across quarters (lanes differing in bits 4,5)
#pragma unroll
  for (int j = 0; j < 16; ++j) {
    acc[j] += __shfl_xor(acc[j], 16, 64);
    acc[j] += __shfl_xor(acc[j], 32, 64);
  }
  sm += __shfl_xor(sm, 16, 64);
  sm += __shfl_xor(sm, 32, 64);
#pragma unroll
  for (int j = 0; j < 16; ++j) acc[j] = fmaf(-128.f, sm, acc[j]);
  // per-node max (quarters now equal; reduce within quarter)
  float mx = 0.f;
#pragma unroll
  for (int j = 0; j < 16; ++j) mx = fmaxf(mx, fabsf(acc[j]));
#pragma unroll
  for (int off = 1; off < 16; off <<= 1) mx = fmaxf(mx, __shfl_xor(mx, off, 64));
  if (lane < 16) {
    float inv = mx > 0.f ? 127.0f / mx : 0.f;
    uint w[4];
#pragma unroll
    for (int t = 0; t < 4; ++t) {
      w[t] = q_u8(acc[t * 4 + 0], inv) | (q_u8(acc[t * 4 + 1], inv) << 8) |
             (q_u8(acc[t * 4 + 2], inv) << 16) | (q_u8(acc[t * 4 + 3], inv) << 24);
    }
    *reinterpret_cast<uint4*>(dst + (size_t)row * 256 + ql * 16) =
        make_uint4(w[0], w[1], w[2], w[3]);
    if (lane == 0) dsc[row] = mx * (1.0f / 127.0f);
  }
}

__global__ __launch_bounds__(256) void spmm_s1(const int* __restrict__ rs,
                                               const uint2* __restrict__ pr,
                                               const uchar* __restrict__ src,
                                               const float* __restrict__ ssc,
                                               uchar* __restrict__ dst,
                                               float* __restrict__ dsc) {
  spmm_body(rs, pr, src, ssc, dst, dsc);
}
__global__ __launch_bounds__(256) void spmm_s2(const int* __restrict__ rs,
                                               const uint2* __restrict__ pr,
                                               const uchar* __restrict__ src,
                                               const float* __restrict__ ssc,
                                               uchar* __restrict__ dst,
                                               float* __restrict__ dsc) {
  spmm_body(rs, pr, src, ssc, dst, dsc);
}
__global__ __launch_bounds__(256) void spmm_s3(const int* __restrict__ rs,
                                               const uint2* __restrict__ pr,
                                               const uchar* __restrict__ src,
                                               const float* __restrict__ ssc,
                                               uchar* __restrict__ dst,
                                               float* __restrict__ dsc) {
  spmm_body(rs, pr, src, ssc, dst, dsc);
}

// dequant 8 biased-u8 -> bf16x8: f = u*sc - 128*sc
__device__ __forceinline__ short8 dequant8_u8(uint2 q, float sc, float nb) {
  float f0 = fmaf((float)(q.x & 0xffu),         sc, nb);
  float f1 = fmaf((float)((q.x >> 8) & 0xffu),  sc, nb);
  float f2 = fmaf((float)((q.x >> 16) & 0xffu), sc, nb);
  float f3 = fmaf((float)(q.x >> 24),           sc, nb);
  float f4 = fmaf((float)(q.y & 0xffu),         sc, nb);
  float f5 = fmaf((float)((q.y >> 8) & 0xffu),  sc, nb);
  float f6 = fmaf((float)((q.y >> 16) & 0xffu), sc, nb);
  float f7 = fmaf((float)(q.y >> 24),           sc, nb);
  uint4 v = make_uint4(pack_bf16(f0, f1), pack_bf16(f2, f3),
                       pack_bf16(f4, f5), pack_bf16(f6, f7));
  return __builtin_bit_cast(short8, v);
}

// out = relu(bias + x@Wt0 + S1@Wt1 + S2@Wt2 + S3@Wt3), MFMA 16x16x32 bf16.
// All four A matrices biased-u8 [node][b][64] + per-node scale.
__global__ __launch_bounds__(256) void gemm4_mfma(
    const uchar* __restrict__ A0u8, const float* __restrict__ A0sc,
    const uchar* __restrict__ A1u8, const float* __restrict__ A1sc,
    const uchar* __restrict__ A2u8, const float* __restrict__ A2sc,
    const uchar* __restrict__ A3u8, const float* __restrict__ A3sc,
    const uint* __restrict__ wtT,   // [64][128] words (bf16 [64][256])
    const float* __restrict__ bias, float* __restrict__ out) {
  __shared__ uint WS[64 * 132];
  __shared__ float bias_s[64];
  for (int w = threadIdx.x; w < 8192; w += 256)
    WS[(w >> 7) * 132 + (w & 127)] = wtT[w];
  if (threadIdx.x < 64) bias_s[threadIdx.x] = bias[threadIdx.x];
  __syncthreads();

  const int lane = threadIdx.x & 63;
  const int wv = threadIdx.x >> 6;
  const int r0 = blockIdx.x * 64 + wv * 16;
  const int c16 = lane & 15;
  const int hi = lane >> 4;

  const int ar = r0 + c16;                         // A row for this lane
  const size_t arow_b = (size_t)ar * 64 + hi * 8;  // u8 byte offset
  const int nd = ar >> 2;
  const float sc0 = A0sc[nd];
  const float sc1 = A1sc[nd];
  const float sc2 = A2sc[nd];
  const float sc3 = A3sc[nd];

  f32x4 acc[4] = {{0.f, 0.f, 0.f, 0.f}, {0.f, 0.f, 0.f, 0.f},
                  {0.f, 0.f, 0.f, 0.f}, {0.f, 0.f, 0.f, 0.f}};

#pragma unroll
  for (int ks = 0; ks < 8; ++ks) {
    const int m = ks >> 1;
    const uchar* Au = (m == 0) ? A0u8 : (m == 1) ? A1u8 : (m == 2) ? A2u8 : A3u8;
    const float sc = (m == 0) ? sc0 : (m == 1) ? sc1 : (m == 2) ? sc2 : sc3;
    uint2 qv = *reinterpret_cast<const uint2*>(Au + arow_b + (ks & 1) * 32);
    short8 afrag = dequant8_u8(qv, sc, -128.f * sc);
#pragma unroll
    for (int nt = 0; nt < 4; ++nt) {
      uint4 bv = *reinterpret_cast<const uint4*>(
          &WS[(nt * 16 + c16) * 132 + ks * 16 + hi * 4]);
      short8 bfrag = __builtin_bit_cast(short8, bv);
      acc[nt] = __builtin_amdgcn_mfma_f32_16x16x32_bf16(afrag, bfrag, acc[nt], 0, 0, 0);
    }
  }

  // C/D layout: col = lane&15, row = (lane>>4)*4 + i  [verified m89/m91]
#pragma unroll
  for (int nt = 0; nt < 4; ++nt) {
#pragma unroll
    for (int i = 0; i < 4; ++i) {
      int row = r0 + hi * 4 + i;
      int node = row >> 2, b = row & 3;
      int col = nt * 16 + c16;
      float v = acc[nt][i] + bias_s[col];
      out[(size_t)b * BN + (size_t)node * 64 + col] = fmaxf(v, 0.f);
    }
  }
}

extern "C" void kernel_launch(void* const* d_in, const int* in_sizes, int n_in,
                              void* d_out, int out_size, void* d_ws, size_t ws_size,
                              hipStream_t stream) {
  const float* x        = (const float*)d_in[0];
  const int*   lap_rows = (const int*)d_in[1];
  const int*   lap_cols = (const int*)d_in[2];
  const float* lap_vals = (const float*)d_in[3];
  const float* weights  = (const float*)d_in[4];  // [4][64][64]
  const float* bias     = (const float*)d_in[5];
  float* out = (float*)d_out;

  char* ws = (char*)d_ws;
  size_t off = 0;
  auto alloc = [&](size_t bytes) {
    void* p = ws + off;
    off += (bytes + 255) & ~(size_t)255;
    return p;
  };
  int*    bcounts     = (int*)alloc((size_t)TOTC * 4);
  int*    bases       = (int*)alloc((size_t)TOTC * 4);
  int*    row_start   = (int*)alloc((size_t)(N_NODES + 1) * 4);
  uint2*  pairs       = (uint2*)alloc((size_t)N_EDGES * 8);
  uint2*  staging     = (uint2*)alloc((size_t)N_EDGES * 8);
  ushort* wtT         = (ushort*)alloc((size_t)64 * 256 * 2);
  uchar*  xu8         = (uchar*)alloc((size_t)N_NODES * 256);  // 12.8MB each
  uchar*  S1u         = (uchar*)alloc((size_t)N_NODES * 256);
  uchar*  S2u         = (uchar*)alloc((size_t)N_NODES * 256);
  uchar*  S3u         = (uchar*)alloc((size_t)N_NODES * 256);
  float*  xsc         = (float*)alloc((size_t)N_NODES * 4);
  float*  S1sc        = (float*)alloc((size_t)N_NODES * 4);
  float*  S2sc        = (float*)alloc((size_t)N_NODES * 4);
  float*  S3sc        = (float*)alloc((size_t)N_NODES * 4);
  (void)ws_size; (void)in_sizes; (void)n_in; (void)out_size;

  // Weight prep + x conversion + CSR build (single-histogram counting sort)
  wprep_kernel<<<64, 256, 0, stream>>>(weights, wtT);
  cvt_kernel<<<N_NODES / 4, 256, 0, stream>>>(x, (uint*)xu8, xsc);
  bucket_hist<<<SCT_BLOCKS, 1024, 0, stream>>>(lap_rows, bcounts);
  scan2_kernel<<<1, 1024, 0, stream>>>(bcounts, bases);
  bucket_scatter<<<SCT_BLOCKS, 1024, 0, stream>>>(lap_rows, lap_cols, lap_vals,
                                                  bases, staging);
  bucket_finalize<<<NB, 256, 0, stream>>>(bases, staging, pairs, row_start);

  const int spmm_blocks = N_NODES / 4;  // 12500, one wave per node row

  // S1 = L x ; S2 = L S1 ; S3 = L S2  (biased-u8 -> biased-u8)
  spmm_s1<<<spmm_blocks, 256, 0, stream>>>(row_start, pairs, xu8, xsc, S1u, S1sc);
  spmm_s2<<<spmm_blocks, 256, 0, stream>>>(row_start, pairs, S1u, S1sc, S2u, S2sc);
  spmm_s3<<<spmm_blocks, 256, 0, stream>>>(row_start, pairs, S2u, S2sc, S3u, S3sc);
  // out = relu(bias + x@Wt0 + S1@Wt1 + S2@Wt2 + S3@Wt3)
  gemm4_mfma<<<ROWS_TOTAL / 64, 256, 0, stream>>>(xu8, xsc, S1u, S1sc, S2u, S2sc,
                                                  S3u, S3sc, (const uint*)wtT,
                                                  bias, out);
}

// Round 16
// 188.718 us; speedup vs baseline: 1.5945x; 1.5945x over previous
//
#include <hip/hip_runtime.h>

// ChebyshevGCNN: out = relu(bias + x@W0 + T1@W1 + T2@W2 + T3@W3)
// Reassociated: S1=Lx, S2=LS1, S3=LS2;  T2=2S2-x, T3=4S3-3S1
//   => out = relu(bias + x@(W0-W2) + S1@(W1-3W3) + S2@(2W2) + S3@(4W3))
// Round 16: fix R15's single-block scan2 (123us, R4 bug class repeated) with
// the proven 3-kernel parallel scan (partial2/scanb2/expand2). Everything else
// unchanged: spmm at the ~5 TB/s random-gather ceiling, single-histogram CSR.

#define N_NODES 50000
#define N_EDGES 800000
#define BATCH 4
#define CH 64
#define BN (N_NODES * CH)             // elems per batch matrix (out layout)
#define ROWS_TOTAL (BATCH * N_NODES)  // 200,000
#define NB 782                        // buckets of 64 rows: 782*64 = 50048
#define EPB 8192                      // edges per block in bucket passes
#define SCT_BLOCKS ((N_EDGES + EPB - 1) / EPB)  // 98
#define TOTC (NB * SCT_BLOCKS)        // 76,636 per-(bucket,block) counts
#define SCAN2_BLOCKS ((TOTC + 1023) / 1024)  // 75

typedef unsigned int uint;
typedef unsigned short ushort;
typedef unsigned char uchar;
typedef __attribute__((ext_vector_type(8))) short short8;   // 8 x bf16
typedef __attribute__((ext_vector_type(4))) float f32x4;

__device__ __forceinline__ uint pack_bf16(float lo, float hi) {
  uint a = __float_as_uint(lo);
  uint b = __float_as_uint(hi);
  a = (a + 0x7fffu + ((a >> 16) & 1u)) >> 16;  // RN-even
  b = (b + 0x7fffu + ((b >> 16) & 1u)) >> 16;
  return a | (b << 16);
}
__device__ __forceinline__ ushort bf16one(float x) {
  uint a = __float_as_uint(x);
  a = (a + 0x7fffu + ((a >> 16) & 1u)) >> 16;
  return (ushort)a;
}
// quantize to biased u8: (rint(v*inv)+128)
__device__ __forceinline__ uint q_u8(float v, float inv) {
  return (uint)((int)rintf(v * inv) + 128) & 0xffu;
}

// ---------------- CSR build: counting sort, single histogram ----------------
// 1: per-(block,bucket) histogram -> bcounts[b * SCT_BLOCKS + blk]
__global__ __launch_bounds__(1024) void bucket_hist(const int* __restrict__ rows,
                                                    int* __restrict__ bcounts) {
  __shared__ int h[NB];
  for (int b = threadIdx.x; b < NB; b += 1024) h[b] = 0;
  __syncthreads();
  int base_e = blockIdx.x * EPB;
#pragma unroll
  for (int j = 0; j < EPB / 1024; ++j) {
    int e = base_e + j * 1024 + threadIdx.x;
    if (e < N_EDGES) atomicAdd(&h[rows[e] >> 6], 1);
  }
  __syncthreads();
  for (int b = threadIdx.x; b < NB; b += 1024)
    bcounts[(size_t)b * SCT_BLOCKS + blockIdx.x] = h[b];
}

// 2a: per-block (1024-wide) sums of bcounts
__global__ __launch_bounds__(1024) void partial2(const int* __restrict__ bc,
                                                 int* __restrict__ bsums) {
  int t = blockIdx.x * 1024 + threadIdx.x;
  int v = (t < TOTC) ? bc[t] : 0;
#pragma unroll
  for (int off = 1; off < 64; off <<= 1) v += __shfl_xor(v, off, 64);
  __shared__ int ws[16];
  if ((threadIdx.x & 63) == 0) ws[threadIdx.x >> 6] = v;
  __syncthreads();
  if (threadIdx.x < 16) {
    int s = ws[threadIdx.x];
#pragma unroll
    for (int off = 1; off < 16; off <<= 1) s += __shfl_xor(s, off, 64);
    if (threadIdx.x == 0) bsums[blockIdx.x] = s;
  }
}

// 2b: exclusive scan of the 75 block sums (one small block)
__global__ __launch_bounds__(128) void scanb2(const int* __restrict__ bsums,
                                              int* __restrict__ boff) {
  __shared__ int s[128];
  int tid = threadIdx.x;
  int v = (tid < SCAN2_BLOCKS) ? bsums[tid] : 0;
  s[tid] = v;
  __syncthreads();
  for (int off = 1; off < 128; off <<= 1) {
    int t = (tid >= off) ? s[tid - off] : 0;
    __syncthreads();
    s[tid] += t;
    __syncthreads();
  }
  boff[tid] = s[tid] - v;  // exclusive
}

// 2c: per-block exclusive scan + global offset -> bases
__global__ __launch_bounds__(1024) void expand2(const int* __restrict__ bc,
                                                const int* __restrict__ boff,
                                                int* __restrict__ bases) {
  int t = blockIdx.x * 1024 + threadIdx.x;
  int tid = threadIdx.x;
  int v = (t < TOTC) ? bc[t] : 0;
  __shared__ int s[1024];
  s[tid] = v;
  __syncthreads();
  for (int off = 1; off < 1024; off <<= 1) {
    int tv = (tid >= off) ? s[tid - off] : 0;
    __syncthreads();
    s[tid] += tv;
    __syncthreads();
  }
  if (t < TOTC) bases[t] = boff[blockIdx.x] + s[tid] - v;
}

// 3: scatter edges; cursors prefilled from scanned bases (single edge loop)
__global__ __launch_bounds__(1024) void bucket_scatter(const int* __restrict__ rows,
                                                       const int* __restrict__ cols,
                                                       const float* __restrict__ vals,
                                                       const int* __restrict__ bases,
                                                       uint2* __restrict__ staging) {
  __shared__ int lcur[NB];
  for (int b = threadIdx.x; b < NB; b += 1024)
    lcur[b] = bases[(size_t)b * SCT_BLOCKS + blockIdx.x];
  __syncthreads();
  int base_e = blockIdx.x * EPB;
#pragma unroll
  for (int j = 0; j < EPB / 1024; ++j) {
    int e = base_e + j * 1024 + threadIdx.x;
    if (e < N_EDGES) {
      int r = rows[e];
      int pos = atomicAdd(&lcur[r >> 6], 1);
      staging[pos] = make_uint2((uint)cols[e] | ((uint)(r & 63) << 20),
                                __float_as_uint(vals[e]));
    }
  }
}

// 4: within each bucket, group by exact row; emit pairs + row_start.
__global__ __launch_bounds__(256) void bucket_finalize(const int* __restrict__ bases,
                                                       const uint2* __restrict__ staging,
                                                       uint2* __restrict__ pairs,
                                                       int* __restrict__ row_start) {
  int b = blockIdx.x;
  int seg0 = bases[(size_t)b * SCT_BLOCKS];
  int seg1 = (b == NB - 1) ? N_EDGES : bases[(size_t)(b + 1) * SCT_BLOCKS];
  __shared__ int hist[64];
  __shared__ int cur[64];
  if (threadIdx.x < 64) hist[threadIdx.x] = 0;
  __syncthreads();
  for (int i = seg0 + threadIdx.x; i < seg1; i += 256)
    atomicAdd(&hist[staging[i].x >> 20], 1);
  __syncthreads();
  if (threadIdx.x < 64) {
    int v = hist[threadIdx.x];
    int sc = v;
#pragma unroll
    for (int off = 1; off < 64; off <<= 1) {
      int t = __shfl_up(sc, off, 64);
      if (threadIdx.x >= (unsigned)off) sc += t;
    }
    int start = seg0 + sc - v;  // exclusive
    cur[threadIdx.x] = start;
    int r = b * 64 + threadIdx.x;
    if (r < N_NODES) row_start[r] = start;
    if (r == N_NODES) row_start[N_NODES] = N_EDGES;
  }
  __syncthreads();
  for (int i = seg0 + threadIdx.x; i < seg1; i += 256) {
    uint2 eu = staging[i];
    int rl = eu.x >> 20;
    int pos = atomicAdd(&cur[rl], 1);
    pairs[pos] = make_uint2(eu.x & 0xFFFFFu, eu.y);
  }
}

// Modified weights, transposed + bf16: wtT[o][k], k = m*64+c, m in 0..3.
__global__ __launch_bounds__(256) void wprep_kernel(const float* __restrict__ w,
                                                    ushort* __restrict__ wtT) {
  int t = blockIdx.x * 256 + threadIdx.x;
  if (t >= 64 * 256) return;
  int o = t >> 8, k = t & 255, m = k >> 6, c = k & 63;
  int idx = c * 64 + o;
  float v;
  if (m == 0)      v = w[idx] - w[2 * 4096 + idx];
  else if (m == 1) v = w[4096 + idx] - 3.0f * w[3 * 4096 + idx];
  else if (m == 2) v = 2.0f * w[2 * 4096 + idx];
  else             v = 4.0f * w[3 * 4096 + idx];
  wtT[t] = bf16one(v);
}

// One wave per node: f32 [b][node][64] -> biased-u8 [node][b][64] + scale.
__global__ __launch_bounds__(256) void cvt_kernel(const float* __restrict__ in,
                                                  uint* __restrict__ xu8w,
                                                  float* __restrict__ xsc) {
  int node = blockIdx.x * 4 + (threadIdx.x >> 6);
  int lane = threadIdx.x & 63;
  int b = lane >> 4;
  int c4 = (lane & 15) * 4;
  float4 v = *reinterpret_cast<const float4*>(in + (size_t)b * BN + (size_t)node * 64 + c4);
  float mx = fmaxf(fmaxf(fabsf(v.x), fabsf(v.y)), fmaxf(fabsf(v.z), fabsf(v.w)));
#pragma unroll
  for (int off = 1; off < 64; off <<= 1) mx = fmaxf(mx, __shfl_xor(mx, off, 64));
  float inv = mx > 0.f ? 127.0f / mx : 0.f;
  uint w8 = q_u8(v.x, inv) | (q_u8(v.y, inv) << 8) |
            (q_u8(v.z, inv) << 16) | (q_u8(v.w, inv) << 24);
  xu8w[(size_t)node * 64 + b * 16 + (lane & 15)] = w8;
  if (lane == 0) xsc[node] = mx * (1.0f / 127.0f);
}

// decode 16 biased-u8 values: acc += m * u (bias handled via sm)
__device__ __forceinline__ void fma16_u8(float acc[16], float& sm, float m,
                                         const uint4& w) {
  const uint arr[4] = {w.x, w.y, w.z, w.w};
#pragma unroll
  for (int t = 0; t < 4; ++t) {
    uint u = arr[t];
    acc[t * 4 + 0] = fmaf(m, (float)(u & 0xffu),         acc[t * 4 + 0]);
    acc[t * 4 + 1] = fmaf(m, (float)((u >> 8) & 0xffu),  acc[t * 4 + 1]);
    acc[t * 4 + 2] = fmaf(m, (float)((u >> 16) & 0xffu), acc[t * 4 + 2]);
    acc[t * 4 + 3] = fmaf(m, (float)(u >> 24),           acc[t * 4 + 3]);
  }
  sm += m;
}

// dst = L * src, biased-u8 in/out, per-node scales. One wave per dest node.
// 16 lanes x 16B = one 256B edge block, 4 edges per VMEM instruction,
// 2-deep unroll (8 edges in flight). value=(u-128)*sc folded via acc-128*sm.
__device__ __forceinline__ void spmm_body(const int* __restrict__ row_start,
                                          const uint2* __restrict__ pairs,
                                          const uchar* __restrict__ src,
                                          const float* __restrict__ ssc,
                                          uchar* __restrict__ dst,
                                          float* __restrict__ dsc) {
  int row = blockIdx.x * 4 + (threadIdx.x >> 6);
  int lane = threadIdx.x & 63;
  int q = lane >> 4;
  int ql = lane & 15;
  const uchar* sb = src + ql * 16;
  int s = row_start[row], e = row_start[row + 1];
  float acc[16];
  float sm = 0.f;
#pragma unroll
  for (int j = 0; j < 16; ++j) acc[j] = 0.f;
  int i = s;
  for (; i + 7 < e; i += 8) {
    uint2 pa = pairs[i + q];
    uint2 pb = pairs[i + 4 + q];
    uint4 qa = *reinterpret_cast<const uint4*>(sb + (size_t)pa.x * 256);
    uint4 qb = *reinterpret_cast<const uint4*>(sb + (size_t)pb.x * 256);
    float ma = __uint_as_float(pa.y) * ssc[pa.x];
    float mb = __uint_as_float(pb.y) * ssc[pb.x];
    fma16_u8(acc, sm, ma, qa);
    fma16_u8(acc, sm, mb, qb);
  }
  for (; i < e; i += 4) {
    if (i + q < e) {
      uint2 p0 = pairs[i + q];
      uint4 q0 = *reinterpret_cast<const uint4*>(sb + (size_t)p0.x * 256);
      fma16_u8(acc, sm, __uint_as_float(p0.y) * ssc[p0.x], q0);
    }
  }
  // fold across quarters (lanes differing in bits 4,5)
#pragma unroll
  for (int j = 0; j < 16; ++j) {
    acc[j] += __shfl_xor(acc[j], 16, 64);
    acc[j] += __shfl_xor(acc[j], 32, 64);
  }
  sm += __shfl_xor(sm, 16, 64);
  sm += __shfl_xor(sm, 32, 64);
#pragma unroll
  for (int j = 0; j < 16; ++j) acc[j] = fmaf(-128.f, sm, acc[j]);
  // per-node max (quarters now equal; reduce within quarter)
  float mx = 0.f;
#pragma unroll
  for (int j = 0; j < 16; ++j) mx = fmaxf(mx, fabsf(acc[j]));
#pragma unroll
  for (int off = 1; off < 16; off <<= 1) mx = fmaxf(mx, __shfl_xor(mx, off, 64));
  if (lane < 16) {
    float inv = mx > 0.f ? 127.0f / mx : 0.f;
    uint w[4];
#pragma unroll
    for (int t = 0; t < 4; ++t) {
      w[t] = q_u8(acc[t * 4 + 0], inv) | (q_u8(acc[t * 4 + 1], inv) << 8) |
             (q_u8(acc[t * 4 + 2], inv) << 16) | (q_u8(acc[t * 4 + 3], inv) << 24);
    }
    *reinterpret_cast<uint4*>(dst + (size_t)row * 256 + ql * 16) =
        make_uint4(w[0], w[1], w[2], w[3]);
    if (lane == 0) dsc[row] = mx * (1.0f / 127.0f);
  }
}

__global__ __launch_bounds__(256) void spmm_s1(const int* __restrict__ rs,
                                               const uint2* __restrict__ pr,
                                               const uchar* __restrict__ src,
                                               const float* __restrict__ ssc,
                                               uchar* __restrict__ dst,
                                               float* __restrict__ dsc) {
  spmm_body(rs, pr, src, ssc, dst, dsc);
}
__global__ __launch_bounds__(256) void spmm_s2(const int* __restrict__ rs,
                                               const uint2* __restrict__ pr,
                                               const uchar* __restrict__ src,
                                               const float* __restrict__ ssc,
                                               uchar* __restrict__ dst,
                                               float* __restrict__ dsc) {
  spmm_body(rs, pr, src, ssc, dst, dsc);
}
__global__ __launch_bounds__(256) void spmm_s3(const int* __restrict__ rs,
                                               const uint2* __restrict__ pr,
                                               const uchar* __restrict__ src,
                                               const float* __restrict__ ssc,
                                               uchar* __restrict__ dst,
                                               float* __restrict__ dsc) {
  spmm_body(rs, pr, src, ssc, dst, dsc);
}

// dequant 8 biased-u8 -> bf16x8: f = u*sc - 128*sc
__device__ __forceinline__ short8 dequant8_u8(uint2 q, float sc, float nb) {
  float f0 = fmaf((float)(q.x & 0xffu),         sc, nb);
  float f1 = fmaf((float)((q.x >> 8) & 0xffu),  sc, nb);
  float f2 = fmaf((float)((q.x >> 16) & 0xffu), sc, nb);
  float f3 = fmaf((float)(q.x >> 24),           sc, nb);
  float f4 = fmaf((float)(q.y & 0xffu),         sc, nb);
  float f5 = fmaf((float)((q.y >> 8) & 0xffu),  sc, nb);
  float f6 = fmaf((float)((q.y >> 16) & 0xffu), sc, nb);
  float f7 = fmaf((float)(q.y >> 24),           sc, nb);
  uint4 v = make_uint4(pack_bf16(f0, f1), pack_bf16(f2, f3),
                       pack_bf16(f4, f5), pack_bf16(f6, f7));
  return __builtin_bit_cast(short8, v);
}

// out = relu(bias + x@Wt0 + S1@Wt1 + S2@Wt2 + S3@Wt3), MFMA 16x16x32 bf16.
// All four A matrices biased-u8 [node][b][64] + per-node scale.
__global__ __launch_bounds__(256) void gemm4_mfma(
    const uchar* __restrict__ A0u8, const float* __restrict__ A0sc,
    const uchar* __restrict__ A1u8, const float* __restrict__ A1sc,
    const uchar* __restrict__ A2u8, const float* __restrict__ A2sc,
    const uchar* __restrict__ A3u8, const float* __restrict__ A3sc,
    const uint* __restrict__ wtT,   // [64][128] words (bf16 [64][256])
    const float* __restrict__ bias, float* __restrict__ out) {
  __shared__ uint WS[64 * 132];
  __shared__ float bias_s[64];
  for (int w = threadIdx.x; w < 8192; w += 256)
    WS[(w >> 7) * 132 + (w & 127)] = wtT[w];
  if (threadIdx.x < 64) bias_s[threadIdx.x] = bias[threadIdx.x];
  __syncthreads();

  const int lane = threadIdx.x & 63;
  const int wv = threadIdx.x >> 6;
  const int r0 = blockIdx.x * 64 + wv * 16;
  const int c16 = lane & 15;
  const int hi = lane >> 4;

  const int ar = r0 + c16;                         // A row for this lane
  const size_t arow_b = (size_t)ar * 64 + hi * 8;  // u8 byte offset
  const int nd = ar >> 2;
  const float sc0 = A0sc[nd];
  const float sc1 = A1sc[nd];
  const float sc2 = A2sc[nd];
  const float sc3 = A3sc[nd];

  f32x4 acc[4] = {{0.f, 0.f, 0.f, 0.f}, {0.f, 0.f, 0.f, 0.f},
                  {0.f, 0.f, 0.f, 0.f}, {0.f, 0.f, 0.f, 0.f}};

#pragma unroll
  for (int ks = 0; ks < 8; ++ks) {
    const int m = ks >> 1;
    const uchar* Au = (m == 0) ? A0u8 : (m == 1) ? A1u8 : (m == 2) ? A2u8 : A3u8;
    const float sc = (m == 0) ? sc0 : (m == 1) ? sc1 : (m == 2) ? sc2 : sc3;
    uint2 qv = *reinterpret_cast<const uint2*>(Au + arow_b + (ks & 1) * 32);
    short8 afrag = dequant8_u8(qv, sc, -128.f * sc);
#pragma unroll
    for (int nt = 0; nt < 4; ++nt) {
      uint4 bv = *reinterpret_cast<const uint4*>(
          &WS[(nt * 16 + c16) * 132 + ks * 16 + hi * 4]);
      short8 bfrag = __builtin_bit_cast(short8, bv);
      acc[nt] = __builtin_amdgcn_mfma_f32_16x16x32_bf16(afrag, bfrag, acc[nt], 0, 0, 0);
    }
  }

  // C/D layout: col = lane&15, row = (lane>>4)*4 + i  [verified m89/m91]
#pragma unroll
  for (int nt = 0; nt < 4; ++nt) {
#pragma unroll
    for (int i = 0; i < 4; ++i) {
      int row = r0 + hi * 4 + i;
      int node = row >> 2, b = row & 3;
      int col = nt * 16 + c16;
      float v = acc[nt][i] + bias_s[col];
      out[(size_t)b * BN + (size_t)node * 64 + col] = fmaxf(v, 0.f);
    }
  }
}

extern "C" void kernel_launch(void* const* d_in, const int* in_sizes, int n_in,
                              void* d_out, int out_size, void* d_ws, size_t ws_size,
                              hipStream_t stream) {
  const float* x        = (const float*)d_in[0];
  const int*   lap_rows = (const int*)d_in[1];
  const int*   lap_cols = (const int*)d_in[2];
  const float* lap_vals = (const float*)d_in[3];
  const float* weights  = (const float*)d_in[4];  // [4][64][64]
  const float* bias     = (const float*)d_in[5];
  float* out = (float*)d_out;

  char* ws = (char*)d_ws;
  size_t off = 0;
  auto alloc = [&](size_t bytes) {
    void* p = ws + off;
    off += (bytes + 255) & ~(size_t)255;
    return p;
  };
  int*    bcounts     = (int*)alloc((size_t)TOTC * 4);
  int*    bases       = (int*)alloc((size_t)TOTC * 4);
  int*    bsums       = (int*)alloc((size_t)128 * 4);
  int*    boff        = (int*)alloc((size_t)128 * 4);
  int*    row_start   = (int*)alloc((size_t)(N_NODES + 1) * 4);
  uint2*  pairs       = (uint2*)alloc((size_t)N_EDGES * 8);
  uint2*  staging     = (uint2*)alloc((size_t)N_EDGES * 8);
  ushort* wtT         = (ushort*)alloc((size_t)64 * 256 * 2);
  uchar*  xu8         = (uchar*)alloc((size_t)N_NODES * 256);  // 12.8MB each
  uchar*  S1u         = (uchar*)alloc((size_t)N_NODES * 256);
  uchar*  S2u         = (uchar*)alloc((size_t)N_NODES * 256);
  uchar*  S3u         = (uchar*)alloc((size_t)N_NODES * 256);
  float*  xsc         = (float*)alloc((size_t)N_NODES * 4);
  float*  S1sc        = (float*)alloc((size_t)N_NODES * 4);
  float*  S2sc        = (float*)alloc((size_t)N_NODES * 4);
  float*  S3sc        = (float*)alloc((size_t)N_NODES * 4);
  (void)ws_size; (void)in_sizes; (void)n_in; (void)out_size;

  // Weight prep + x conversion + CSR build (single-histogram counting sort)
  wprep_kernel<<<64, 256, 0, stream>>>(weights, wtT);
  cvt_kernel<<<N_NODES / 4, 256, 0, stream>>>(x, (uint*)xu8, xsc);
  bucket_hist<<<SCT_BLOCKS, 1024, 0, stream>>>(lap_rows, bcounts);
  partial2<<<SCAN2_BLOCKS, 1024, 0, stream>>>(bcounts, bsums);
  scanb2<<<1, 128, 0, stream>>>(bsums, boff);
  expand2<<<SCAN2_BLOCKS, 1024, 0, stream>>>(bcounts, boff, bases);
  bucket_scatter<<<SCT_BLOCKS, 1024, 0, stream>>>(lap_rows, lap_cols, lap_vals,
                                                  bases, staging);
  bucket_finalize<<<NB, 256, 0, stream>>>(bases, staging, pairs, row_start);

  const int spmm_blocks = N_NODES / 4;  // 12500, one wave per node row

  // S1 = L x ; S2 = L S1 ; S3 = L S2  (biased-u8 -> biased-u8)
  spmm_s1<<<spmm_blocks, 256, 0, stream>>>(row_start, pairs, xu8, xsc, S1u, S1sc);
  spmm_s2<<<spmm_blocks, 256, 0, stream>>>(row_start, pairs, S1u, S1sc, S2u, S2sc);
  spmm_s3<<<spmm_blocks, 256, 0, stream>>>(row_start, pairs, S2u, S2sc, S3u, S3sc);
  // out = relu(bias + x@Wt0 + S1@Wt1 + S2@Wt2 + S3@Wt3)
  gemm4_mfma<<<ROWS_TOTAL / 64, 256, 0, stream>>>(xu8, xsc, S1u, S1sc, S2u, S2sc,
                                                  S3u, S3sc, (const uint*)wtT,
                                                  bias, out);
}